// Round 14
// baseline (331.969 us; speedup 1.0000x reference)
//
#include <hip/hip_runtime.h>
#include <hip/hip_bf16.h>

#define NB 2
#define SEQ 2048
#define DMODEL 2048
#define NH 16
#define HD 128
// SM_SCALE * log2(e): softmax computed in exp2 domain
#define QSCALE (0.08838834764831845f * 1.44269504088896f)
#define THRL2 11.5f

using bf16x8 = __attribute__((ext_vector_type(8))) __bf16;
using f32x4  = __attribute__((ext_vector_type(4))) float;

#define MFMA16 __builtin_amdgcn_mfma_f32_16x16x32_bf16

typedef __attribute__((address_space(1))) const void* gptr_t;
typedef __attribute__((address_space(3))) void* lptr_t;

__device__ inline void gload_lds16(const unsigned short* g, unsigned short* l) {
    __builtin_amdgcn_global_load_lds((gptr_t)g, (lptr_t)l, 16, 0, 0);
}

__device__ inline unsigned short f2b(float f) {
    unsigned u = __builtin_bit_cast(unsigned, f);
    u += 0x7FFF + ((u >> 16) & 1);
    return (unsigned short)(u >> 16);
}
__device__ inline float b2f(unsigned short h) {
    return __builtin_bit_cast(float, (unsigned)h << 16);
}
__device__ inline float fexp2(float x) {
    float r;
    asm("v_exp_f32 %0, %1" : "=v"(r) : "v"(x));
    return r;
}
__device__ inline unsigned cvtpk(float a, float b) {   // low=bf16(a), high=bf16(b)
    unsigned r;
    asm("v_cvt_pk_bf16_f32 %0, %1, %2" : "=v"(r) : "v"(a), "v"(b));
    return r;
}

// ---------------- cast fp32 -> bf16, 4 elems/thread ----------------
__global__ void cast_f2b(const float* __restrict__ src, unsigned short* __restrict__ dst, int n) {
    int i = (blockIdx.x * 256 + threadIdx.x) * 4;
    if (i + 3 < n) {
        float4 v = *reinterpret_cast<const float4*>(src + i);
        ushort4 o;
        o.x = f2b(v.x); o.y = f2b(v.y); o.z = f2b(v.z); o.w = f2b(v.w);
        *reinterpret_cast<ushort4*>(dst + i) = o;
    }
}

// ================= GEMM 256x256, fine-grained 4-phase/K-tile (m201 port) =================
// 8 waves (2M x 4N), per-wave 128x64 output (acc[8][4]), BK=64 split in 2 K-halves.
// LDS 128KB: 2 buffers x [A 2x(256x32) | B 2x(256x32)], zero-conflict sub-tile layout
// (slot = g ^ ((row>>1)&3), verified 0 conflicts in r13). Staging quantum = one K-half
// of A or B (16KB = 2 gload_lds/thread); 4 half-stages per tile spread over 4 phases.
// vmcnt(4) twice per tile, placed BEFORE the trailing s_barrier (cross-wave guarantee).
template<int OUT_BF16>
__global__ __launch_bounds__(512) void gemm256(const unsigned short* __restrict__ A,
                                               const unsigned short* __restrict__ Bw,
                                               void* __restrict__ Cout,
                                               int M, int N, int K) {
    __shared__ __align__(16) char lds[131072];   // buf b at b*65536: [A 32K][B 32K]
    int tid = threadIdx.x;
    int lane = tid & 63;
    int wid = tid >> 6;
    int wm = wid >> 2, wn = wid & 3;             // 2 x 4 waves
    int row0 = blockIdx.y * 256;
    int col0 = blockIdx.x * 256;
    int lr = lane & 15, g = lane >> 4;

    // staging: one K-half of one matrix = 256 rows x 32 shorts = 1024 chunks; 2 loads/thread
    // chunk = i*512 + tid -> row = chunk>>2, c = chunk&3; slot c holds k-chunk c^((row>>1)&3)
    const unsigned short *pA[2], *pB[2];
    int ldsc[2];
#pragma unroll
    for (int i = 0; i < 2; i++) {
        int chunk = i * 512 + tid;
        int row = chunk >> 2, c = chunk & 3;
        int cs = c ^ ((row >> 1) & 3);
        pA[i] = A  + (size_t)(row0 + row) * K + cs * 8;
        pB[i] = Bw + (size_t)(col0 + row) * K + cs * 8;
        ldsc[i] = (i * 512 + (tid & ~63)) * 16;  // wave-uniform dest base (HW adds lane*16)
    }

#define STAGE_A(bufb, kbase, h)  {                                                    \
        _Pragma("unroll")                                                             \
        for (int i_ = 0; i_ < 2; i_++)                                                \
            gload_lds16(pA[i_] + (kbase) + (h) * 32,                                  \
                (unsigned short*)(lds + (bufb) + (h) * 16384 + ldsc[i_]));            \
    }
#define STAGE_B(bufb, kbase, h)  {                                                    \
        _Pragma("unroll")                                                             \
        for (int i_ = 0; i_ < 2; i_++)                                                \
            gload_lds16(pB[i_] + (kbase) + (h) * 32,                                  \
                (unsigned short*)(lds + (bufb) + 32768 + (h) * 16384 + ldsc[i_]));    \
    }

    // fragment read offsets (relative to buffer base); zero-conflict slot XOR
    int offA[8][2], offB[4][2];
#pragma unroll
    for (int i = 0; i < 8; i++) {
        int row = wm * 128 + i * 16 + lr;
#pragma unroll
        for (int ks = 0; ks < 2; ks++)
            offA[i][ks] = ks * 16384 + row * 64 + ((g ^ ((row >> 1) & 3)) * 16);
    }
#pragma unroll
    for (int j = 0; j < 4; j++) {
        int row = wn * 64 + j * 16 + lr;
#pragma unroll
        for (int ks = 0; ks < 2; ks++)
            offB[j][ks] = 32768 + ks * 16384 + row * 64 + ((g ^ ((row >> 1) & 3)) * 16);
    }

    f32x4 acc[8][4] = {};
    int NT = K >> 6;

    // prologue: stage tile 0 fully (order Ak0, Bk0, Ak1, Bk1), k0 landed -> barrier
    STAGE_A(0, 0, 0); STAGE_B(0, 0, 0); STAGE_A(0, 0, 1); STAGE_B(0, 0, 1);
    asm volatile("s_waitcnt vmcnt(4)" ::: "memory");   // Ak0+Bk0 landed; k1 in flight
    __builtin_amdgcn_s_barrier();
    __builtin_amdgcn_sched_barrier(0);

    for (int t = 0; t < NT; ++t) {
        const char* bufc = lds + (t & 1) * 65536;
        int bufn = ((t + 1) & 1) * 65536;
        bool hn = (t + 1 < NT);
        int kn = (t + 1) * 64;

        bf16x8 av[4], bv[4];

        // ---------- phase 0: ks0, A rows 0-3 (+ all B ks0) ----------
#pragma unroll
        for (int j = 0; j < 4; j++) bv[j] = *reinterpret_cast<const bf16x8*>(bufc + offB[j][0]);
#pragma unroll
        for (int i = 0; i < 4; i++) av[i] = *reinterpret_cast<const bf16x8*>(bufc + offA[i][0]);
        if (hn) STAGE_A(bufn, kn, 0);
        __builtin_amdgcn_s_barrier();
        asm volatile("s_waitcnt lgkmcnt(0)" ::: "memory");
        __builtin_amdgcn_sched_barrier(0);
        __builtin_amdgcn_s_setprio(1);
#pragma unroll
        for (int i = 0; i < 4; i++)
#pragma unroll
            for (int j = 0; j < 4; j++)
                acc[i][j] = MFMA16(av[i], bv[j], acc[i][j], 0, 0, 0);
        __builtin_amdgcn_s_setprio(0);
        __builtin_amdgcn_s_barrier();
        __builtin_amdgcn_sched_barrier(0);

        // ---------- phase 1: ks0, A rows 4-7 ----------
#pragma unroll
        for (int i = 0; i < 4; i++) av[i] = *reinterpret_cast<const bf16x8*>(bufc + offA[4 + i][0]);
        if (hn) STAGE_B(bufn, kn, 0);
        __builtin_amdgcn_s_barrier();
        asm volatile("s_waitcnt lgkmcnt(0)" ::: "memory");
        __builtin_amdgcn_sched_barrier(0);
        __builtin_amdgcn_s_setprio(1);
#pragma unroll
        for (int i = 0; i < 4; i++)
#pragma unroll
            for (int j = 0; j < 4; j++)
                acc[4 + i][j] = MFMA16(av[i], bv[j], acc[4 + i][j], 0, 0, 0);
        __builtin_amdgcn_s_setprio(0);
        // ensure current tile's k1 halves landed (cross-wave after the barrier)
        if (hn) asm volatile("s_waitcnt vmcnt(4)" ::: "memory");
        else    asm volatile("s_waitcnt vmcnt(0)" ::: "memory");
        __builtin_amdgcn_s_barrier();
        __builtin_amdgcn_sched_barrier(0);

        // ---------- phase 2: ks1, A rows 0-3 (+ all B ks1) ----------
#pragma unroll
        for (int j = 0; j < 4; j++) bv[j] = *reinterpret_cast<const bf16x8*>(bufc + offB[j][1]);
#pragma unroll
        for (int i = 0; i < 4; i++) av[i] = *reinterpret_cast<const bf16x8*>(bufc + offA[i][1]);
        if (hn) STAGE_A(bufn, kn, 1);
        __builtin_amdgcn_s_barrier();
        asm volatile("s_waitcnt lgkmcnt(0)" ::: "memory");
        __builtin_amdgcn_sched_barrier(0);
        __builtin_amdgcn_s_setprio(1);
#pragma unroll
        for (int i = 0; i < 4; i++)
#pragma unroll
            for (int j = 0; j < 4; j++)
                acc[i][j] = MFMA16(av[i], bv[j], acc[i][j], 0, 0, 0);
        __builtin_amdgcn_s_setprio(0);
        __builtin_amdgcn_s_barrier();
        __builtin_amdgcn_sched_barrier(0);

        // ---------- phase 3: ks1, A rows 4-7 ----------
#pragma unroll
        for (int i = 0; i < 4; i++) av[i] = *reinterpret_cast<const bf16x8*>(bufc + offA[4 + i][1]);
        if (hn) STAGE_B(bufn, kn, 1);
        __builtin_amdgcn_s_barrier();
        asm volatile("s_waitcnt lgkmcnt(0)" ::: "memory");
        __builtin_amdgcn_sched_barrier(0);
        __builtin_amdgcn_s_setprio(1);
#pragma unroll
        for (int i = 0; i < 4; i++)
#pragma unroll
            for (int j = 0; j < 4; j++)
                acc[4 + i][j] = MFMA16(av[i], bv[j], acc[4 + i][j], 0, 0, 0);
        __builtin_amdgcn_s_setprio(0);
        // next tile's k0 halves landed before its phase 0 reads (cross-wave after barrier)
        if (hn) asm volatile("s_waitcnt vmcnt(4)" ::: "memory");
        __builtin_amdgcn_s_barrier();
        __builtin_amdgcn_sched_barrier(0);
    }
#undef STAGE_A
#undef STAGE_B

    int orow = g * 4;
#pragma unroll
    for (int i = 0; i < 8; i++) {
#pragma unroll
        for (int j = 0; j < 4; j++) {
            int r0 = row0 + wm * 128 + i * 16 + orow;
            int c  = col0 + wn * 64 + j * 16 + lr;
#pragma unroll
            for (int r = 0; r < 4; r++) {
                float v = acc[i][j][r];
                if (OUT_BF16)
                    ((unsigned short*)Cout)[(size_t)(r0 + r) * N + c] = f2b(v);
                else
                    ((float*)Cout)[(size_t)(r0 + r) * N + c] = v;
            }
        }
    }
}

// ---------------- GEMM 128x256 2-phase (round-13-verified) — used for out-proj ----------------
template<int OUT_BF16>
__global__ __launch_bounds__(512) void gemm8p(const unsigned short* __restrict__ A,
                                              const unsigned short* __restrict__ Bw,
                                              void* __restrict__ Cout,
                                              int M, int N, int K) {
    __shared__ __align__(16) char lds[98304];   // [A0 16K][B0 32K][A1 16K][B1 32K]
    int tid = threadIdx.x;
    int lane = tid & 63;
    int wid = tid >> 6;
    int wm = wid >> 2, wn = wid & 3;
    int row0 = blockIdx.y * 128;
    int col0 = blockIdx.x * 256;
    int lr = lane & 15, g = lane >> 4;

    const unsigned short* srcA[2];
    const unsigned short* srcB[4];
#pragma unroll
    for (int i = 0; i < 2; i++) {
        int chunk = i * 512 + tid;
        int ksub = chunk >> 9;
        int cw = chunk & 511;
        int row = cw >> 2, c = cw & 3;
        int cs = c ^ ((row >> 1) & 3);
        srcA[i] = A + (size_t)(row0 + row) * K + ksub * 32 + cs * 8;
    }
#pragma unroll
    for (int i = 0; i < 4; i++) {
        int chunk = i * 512 + tid;
        int ksub = chunk >> 10;
        int cw = chunk & 1023;
        int row = cw >> 2, c = cw & 3;
        int cs = c ^ ((row >> 1) & 3);
        srcB[i] = Bw + (size_t)(col0 + row) * K + ksub * 32 + cs * 8;
    }

    int offA[4][2], offB[4][2];
#pragma unroll
    for (int i = 0; i < 4; i++) {
        int row = wm * 64 + i * 16 + lr;
#pragma unroll
        for (int ks = 0; ks < 2; ks++)
            offA[i][ks] = ks * 8192 + row * 64 + ((g ^ ((row >> 1) & 3)) * 16);
    }
#pragma unroll
    for (int j = 0; j < 4; j++) {
        int row = wn * 64 + j * 16 + lr;
#pragma unroll
        for (int ks = 0; ks < 2; ks++)
            offB[j][ks] = ks * 16384 + row * 64 + ((g ^ ((row >> 1) & 3)) * 16);
    }

    f32x4 acc[4][4] = {};
    int NT = K >> 6;

#define STAGE8(t) {                                                                   \
        int kb_ = (t) * 64;                                                           \
        int bs_ = ((t) & 1) * 49152;                                                  \
        _Pragma("unroll")                                                             \
        for (int i_ = 0; i_ < 2; i_++)                                                \
            gload_lds16(srcA[i_] + kb_,                                               \
                (unsigned short*)(lds + bs_ + (i_ * 512 + (tid & ~63)) * 16));        \
        _Pragma("unroll")                                                             \
        for (int i_ = 0; i_ < 4; i_++)                                                \
            gload_lds16(srcB[i_] + kb_,                                               \
                (unsigned short*)(lds + bs_ + 16384 + (i_ * 512 + (tid & ~63)) * 16)); \
    }

    STAGE8(0);
    for (int t = 0; t < NT; ++t) {
        if (t + 1 < NT) {
            STAGE8(t + 1);
            asm volatile("s_waitcnt vmcnt(6)" ::: "memory");
        } else {
            asm volatile("s_waitcnt vmcnt(0)" ::: "memory");
        }
        __builtin_amdgcn_s_barrier();
        __builtin_amdgcn_sched_barrier(0);

        const char* ab = lds + (t & 1) * 49152;
        const char* bb = ab + 16384;

        bf16x8 b[4][2], a[2][2];
#pragma unroll
        for (int j = 0; j < 4; j++)
#pragma unroll
            for (int ks = 0; ks < 2; ks++)
                b[j][ks] = *reinterpret_cast<const bf16x8*>(bb + offB[j][ks]);
#pragma unroll
        for (int i = 0; i < 2; i++)
#pragma unroll
            for (int ks = 0; ks < 2; ks++)
                a[i][ks] = *reinterpret_cast<const bf16x8*>(ab + offA[i][ks]);
        asm volatile("s_waitcnt lgkmcnt(0)" ::: "memory");
        __builtin_amdgcn_sched_barrier(0);
        __builtin_amdgcn_s_setprio(1);
#pragma unroll
        for (int ks = 0; ks < 2; ks++)
#pragma unroll
            for (int i = 0; i < 2; i++)
#pragma unroll
                for (int j = 0; j < 4; j++)
                    acc[i][j] = MFMA16(a[i][ks], b[j][ks], acc[i][j], 0, 0, 0);
        __builtin_amdgcn_s_setprio(0);

        bf16x8 a2[2][2];
#pragma unroll
        for (int i = 0; i < 2; i++)
#pragma unroll
            for (int ks = 0; ks < 2; ks++)
                a2[i][ks] = *reinterpret_cast<const bf16x8*>(ab + offA[2 + i][ks]);
        asm volatile("s_waitcnt lgkmcnt(0)" ::: "memory");
        __builtin_amdgcn_sched_barrier(0);
        __builtin_amdgcn_s_barrier();
        __builtin_amdgcn_sched_barrier(0);
        __builtin_amdgcn_s_setprio(1);
#pragma unroll
        for (int ks = 0; ks < 2; ks++)
#pragma unroll
            for (int i = 0; i < 2; i++)
#pragma unroll
                for (int j = 0; j < 4; j++)
                    acc[2 + i][j] = MFMA16(a2[i][ks], b[j][ks], acc[2 + i][j], 0, 0, 0);
        __builtin_amdgcn_s_setprio(0);
    }
#undef STAGE8

    int orow = g * 4;
#pragma unroll
    for (int i = 0; i < 4; i++) {
#pragma unroll
        for (int j = 0; j < 4; j++) {
            int r0 = row0 + wm * 64 + i * 16 + orow;
            int c  = col0 + wn * 64 + j * 16 + lr;
#pragma unroll
            for (int r = 0; r < 4; r++) {
                float v = acc[i][j][r];
                if (OUT_BF16)
                    ((unsigned short*)Cout)[(size_t)(r0 + r) * N + c] = f2b(v);
                else
                    ((float*)Cout)[(size_t)(r0 + r) * N + c] = v;
            }
        }
    }
}

// ---------------- RoPE + rearrange Q,K (Q pre-scaled by SM_SCALE*log2e) ----------------
__global__ void rope_qk(const unsigned short* __restrict__ qkv,
                        unsigned short* __restrict__ qb,
                        unsigned short* __restrict__ kb) {
    int idx = blockIdx.x * 256 + threadIdx.x;
    int i = idx & 63;
    int h = (idx >> 6) & 15;
    int t = idx >> 10;
    int s = t & (SEQ - 1);
    int b = t >> 11;

    float inv = exp2f(-13.287712379549449f * (float)i * (1.0f / 64.0f));
    float ang = (float)s * inv;
    float sn, cs;
    sincosf(ang, &sn, &cs);

    const unsigned short* base = qkv + (size_t)t * 6144 + h * 128 + 2 * i;
    unsigned qv = *reinterpret_cast<const unsigned*>(base);
    unsigned kv = *reinterpret_cast<const unsigned*>(base + 2048);

    float qe = b2f((unsigned short)(qv & 0xFFFF));
    float qo = b2f((unsigned short)(qv >> 16));
    float ke = b2f((unsigned short)(kv & 0xFFFF));
    float ko = b2f((unsigned short)(kv >> 16));

    float qe2 = (qe * cs - qo * sn) * QSCALE;
    float qo2 = (qe * sn + qo * cs) * QSCALE;
    float ke2 = ke * cs - ko * sn;
    float ko2 = ke * sn + ko * cs;

    size_t o = ((size_t)(b * NH + h) * SEQ + s) * HD + 2 * i;
    *reinterpret_cast<unsigned*>(qb + o) = (unsigned)f2b(qe2) | ((unsigned)f2b(qo2) << 16);
    *reinterpret_cast<unsigned*>(kb + o) = (unsigned)f2b(ke2) | ((unsigned)f2b(ko2) << 16);
}

// ---------------- V rearrange: qkv -> vt [B][H][HD][S] ----------------
__global__ void v_rearr(const unsigned short* __restrict__ qkv, unsigned short* __restrict__ vt) {
    int idx = blockIdx.x * 256 + threadIdx.x;
    int s4 = (idx & 511) * 4;
    int d  = (idx >> 9) & 127;
    int h  = (idx >> 16) & 15;
    int b  = idx >> 20;
    ushort4 o;
    size_t rbase = (size_t)(b * SEQ + s4) * 6144 + 4096 + h * 128 + d;
    o.x = qkv[rbase];
    o.y = qkv[rbase + 6144];
    o.z = qkv[rbase + 2 * 6144];
    o.w = qkv[rbase + 3 * 6144];
    *reinterpret_cast<ushort4*>(vt + ((size_t)(b * NH + h) * HD + d) * SEQ + s4) = o;
}

// ---------------- flash attention v6 (unchanged) ----------------
__global__ __launch_bounds__(64, 1) void attn6(const unsigned short* __restrict__ Q,
                                               const unsigned short* __restrict__ Kb,
                                               const unsigned short* __restrict__ Vt,
                                               unsigned short* __restrict__ O) {
    __shared__ __align__(16) char lds[36864];   // 2x16KB K dbuf + 4KB P

    int lane = threadIdx.x;
    int bid = blockIdx.x;
    int p  = bid >> 5;
    int bh = bid & 31;
    int lr = lane & 15;
    int g  = lane >> 4;
    int g4 = g * 4;
    int lk = g * 8;

    const unsigned short* Qp = Q  + (size_t)bh * SEQ * HD;
    const unsigned short* Kp = Kb + (size_t)bh * SEQ * HD;
    const unsigned short* Vp = Vt + (size_t)bh * HD * SEQ;
    char* pl = lds + 32768;
    int b = bh >> 4;
    int h = bh & 15;

    int srcoff[16];
#pragma unroll
    for (int i2 = 0; i2 < 16; ++i2) {
        int r = i2 * 4 + g;
        srcoff[i2] = r * HD + ((lr ^ (r & 7)) * 8);
    }

#define STAGEK(bufbase, kvbase)                                                     \
    {                                                                               \
        const unsigned short* kbase = Kp + (size_t)(kvbase) * HD;                   \
        _Pragma("unroll")                                                           \
        for (int i2 = 0; i2 < 16; ++i2)                                             \
            gload_lds16(kbase + srcoff[i2],                                         \
                        (unsigned short*)(lds + (bufbase) + i2 * 1024));            \
    }

    for (int ph = 0; ph < 2; ++ph) {
        int j  = ph ? (63 - p) : p;
        int q0 = j * 32;
        int ktiles = (j >> 1) + 1;

        bf16x8 qf[2][4];
#pragma unroll
        for (int f = 0; f < 2; f++)
#pragma unroll
            for (int kb = 0; kb < 4; kb++)
                qf[f][kb] = *reinterpret_cast<const bf16x8*>(Qp + (size_t)(q0 + f * 16 + lr) * HD + kb * 32 + lk);

        f32x4 oacc[2][8] = {};
        float m[2] = { -1e30f, -1e30f }, l[2] = { 0.0f, 0.0f };
        int qrow[2] = { q0 + lr, q0 + 16 + lr };

        STAGEK(0, 0);

        int cur = 0;
        for (int t = 0; t < ktiles; ++t) {
            int kv0 = t * 64;
            if (t + 1 < ktiles) {
                STAGEK((cur ^ 1) * 16384, kv0 + 64);
                asm volatile("s_waitcnt vmcnt(16)" ::: "memory");
            } else {
                asm volatile("s_waitcnt vmcnt(0)" ::: "memory");
            }
            __builtin_amdgcn_sched_barrier(0);

            char* kb_c = lds + cur * 16384;
            f32x4 s[2][4] = {};
#pragma unroll
            for (int kb = 0; kb < 4; kb++) {
#pragma unroll
                for (int jj = 0; jj < 4; jj++) {
                    int row = jj * 16 + lr;
                    int cin = ((kb * 4 + g) ^ (row & 7));
                    bf16x8 kf = *reinterpret_cast<const bf16x8*>(kb_c + row * 256 + cin * 16);
                    s[0][jj] = MFMA16(kf, qf[0][kb], s[0][jj], 0, 0, 0);
                    s[1][jj] = MFMA16(kf, qf[1][kb], s[1][jj], 0, 0, 0);
                }
            }

            bf16x8 vf[8][2];
#pragma unroll
            for (int db = 0; db < 8; db++)
#pragma unroll
                for (int ks = 0; ks < 2; ks++)
                    vf[db][ks] = *reinterpret_cast<const bf16x8*>(Vp + (size_t)(db * 16 + lr) * SEQ + kv0 + ks * 32 + lk);

#pragma unroll
            for (int f = 0; f < 2; f++) {
                int q = qrow[f];
                bool full = (kv0 + 63 <= q0 + f * 16);
                float mx = -1e30f;
                if (full) {
#pragma unroll
                    for (int jj = 0; jj < 4; jj++)
#pragma unroll
                        for (int r = 0; r < 4; r++)
                            mx = fmaxf(mx, s[f][jj][r]);
                } else {
#pragma unroll
                    for (int jj = 0; jj < 4; jj++)
#pragma unroll
                        for (int r = 0; r < 4; r++) {
                            int kv = kv0 + jj * 16 + g4 + r;
                            float v = (kv <= q) ? s[f][jj][r] : -1e30f;
                            s[f][jj][r] = v;
                            mx = fmaxf(mx, v);
                        }
                }
                mx = fmaxf(mx, __shfl_xor(mx, 16));
                mx = fmaxf(mx, __shfl_xor(mx, 32));

                if (!__all(mx <= m[f] + THRL2)) {
                    float mn = fmaxf(m[f], mx);
                    float sc = fexp2(m[f] - mn);
                    m[f] = mn;
                    l[f] *= sc;
#pragma unroll
                    for (int db = 0; db < 8; db++)
#pragma unroll
                        for (int r = 0; r < 4; r++)
                            oacc[f][db][r] *= sc;
                }

                int row = f * 16 + lr;
                int rb = row * 128;
                int sw = (row & 7) << 4;
                float rs = 0.0f;
#pragma unroll
                for (int jj = 0; jj < 4; jj++)
#pragma unroll
                    for (int hh = 0; hh < 2; hh++) {
                        float p0 = fexp2(s[f][jj][2 * hh]     - m[f]);
                        float p1 = fexp2(s[f][jj][2 * hh + 1] - m[f]);
                        rs += p0 + p1;
                        unsigned pk = cvtpk(p0, p1);
                        int colb = jj * 32 + g * 8 + 4 * hh;
                        *reinterpret_cast<unsigned*>(pl + rb + (colb ^ sw)) = pk;
                    }
                rs += __shfl_xor(rs, 16);
                rs += __shfl_xor(rs, 32);
                l[f] += rs;
            }

            asm volatile("s_waitcnt lgkmcnt(0)" ::: "memory");
            __builtin_amdgcn_sched_barrier(0);

            bf16x8 pb[2][2];
#pragma unroll
            for (int f = 0; f < 2; f++)
#pragma unroll
                for (int ks = 0; ks < 2; ks++) {
                    int row = f * 16 + lr;
                    int off = row * 128 + ((ks * 64 + g * 16) ^ ((row & 7) << 4));
                    pb[f][ks] = *reinterpret_cast<const bf16x8*>(pl + off);
                }
#pragma unroll
            for (int db = 0; db < 8; db++)
#pragma unroll
                for (int ks = 0; ks < 2; ks++) {
                    oacc[0][db] = MFMA16(vf[db][ks], pb[0][ks], oacc[0][db], 0, 0, 0);
                    oacc[1][db] = MFMA16(vf[db][ks], pb[1][ks], oacc[1][db], 0, 0, 0);
                }

            cur ^= 1;
        }

#pragma unroll
        for (int f = 0; f < 2; f++) {
            float inv = 1.0f / l[f];
            int q = q0 + f * 16 + lr;
            unsigned short* op = O + ((size_t)(b * SEQ + q)) * DMODEL + h * HD;
#pragma unroll
            for (int db = 0; db < 8; db++) {
                ushort4 o4;
                o4.x = f2b(oacc[f][db][0] * inv);
                o4.y = f2b(oacc[f][db][1] * inv);
                o4.z = f2b(oacc[f][db][2] * inv);
                o4.w = f2b(oacc[f][db][3] * inv);
                *reinterpret_cast<ushort4*>(op + db * 16 + g4) = o4;
            }
        }
    }
#undef STAGEK
}

extern "C" void kernel_launch(void* const* d_in, const int* in_sizes, int n_in,
                              void* d_out, int out_size, void* d_ws, size_t ws_size,
                              hipStream_t stream) {
    const float* x   = (const float*)d_in[0];
    const float* wqk = (const float*)d_in[1];
    const float* wv  = (const float*)d_in[2];
    const float* wo  = (const float*)d_in[3];

    unsigned short* xb  = (unsigned short*)d_ws;            // [4096][2048]
    unsigned short* wb  = xb  + (size_t)8388608;            // [8192][2048]: wqk | wv | wo
    unsigned short* qkv = wb  + (size_t)16777216;           // [4096][6144]
    unsigned short* qb  = qkv + (size_t)25165824;           // [B][H][S][HD]
    unsigned short* kb  = qb  + (size_t)8388608;
    unsigned short* vt  = kb  + (size_t)8388608;            // [B][H][HD][S]
    unsigned short* ao  = vt  + (size_t)8388608;            // [4096][2048]

    cast_f2b<<<8192, 256, 0, stream>>>(x,   xb, 8388608);
    cast_f2b<<<8192, 256, 0, stream>>>(wqk, wb, 8388608);
    cast_f2b<<<4096, 256, 0, stream>>>(wv,  wb + 8388608, 4194304);
    cast_f2b<<<4096, 256, 0, stream>>>(wo,  wb + 12582912, 4194304);

    // QKV projection: 256^2 tiles, fine 4-phase schedule (24 x 16 = 384 blocks)
    gemm256<1><<<dim3(24, 16), 512, 0, stream>>>(xb, wb, (void*)qkv, 4096, 6144, 2048);

    rope_qk<<<16384, 256, 0, stream>>>(qkv, qb, kb);
    v_rearr<<<8192, 256, 0, stream>>>(qkv, vt);

    attn6<<<1024, 64, 0, stream>>>(qb, kb, vt, ao);

    // out projection: 128x256 2-phase kernel (256 blocks = 1 exact CU round)
    gemm8p<0><<<dim3(8, 32), 512, 0, stream>>>(ao, wb + 12582912, d_out, 4096, 2048, 2048);
}

// Round 15
// 326.198 us; speedup vs baseline: 1.0177x; 1.0177x over previous
//
#include <hip/hip_runtime.h>
#include <hip/hip_bf16.h>

#define NB 2
#define SEQ 2048
#define DMODEL 2048
#define NH 16
#define HD 128
// SM_SCALE * log2(e): softmax computed in exp2 domain
#define QSCALE (0.08838834764831845f * 1.44269504088896f)
#define THRL2 11.5f

using bf16x8 = __attribute__((ext_vector_type(8))) __bf16;
using f32x4  = __attribute__((ext_vector_type(4))) float;

#define MFMA16 __builtin_amdgcn_mfma_f32_16x16x32_bf16

typedef __attribute__((address_space(1))) const void* gptr_t;
typedef __attribute__((address_space(3))) void* lptr_t;

__device__ inline void gload_lds16(const unsigned short* g, unsigned short* l) {
    __builtin_amdgcn_global_load_lds((gptr_t)g, (lptr_t)l, 16, 0, 0);
}

__device__ inline unsigned short f2b(float f) {
    unsigned u = __builtin_bit_cast(unsigned, f);
    u += 0x7FFF + ((u >> 16) & 1);
    return (unsigned short)(u >> 16);
}
__device__ inline float b2f(unsigned short h) {
    return __builtin_bit_cast(float, (unsigned)h << 16);
}
__device__ inline float fexp2(float x) {
    float r;
    asm("v_exp_f32 %0, %1" : "=v"(r) : "v"(x));
    return r;
}
__device__ inline unsigned cvtpk(float a, float b) {   // low=bf16(a), high=bf16(b)
    unsigned r;
    asm("v_cvt_pk_bf16_f32 %0, %1, %2" : "=v"(r) : "v"(a), "v"(b));
    return r;
}

// ---------------- cast fp32 -> bf16, 4 elems/thread ----------------
__global__ void cast_f2b(const float* __restrict__ src, unsigned short* __restrict__ dst, int n) {
    int i = (blockIdx.x * 256 + threadIdx.x) * 4;
    if (i + 3 < n) {
        float4 v = *reinterpret_cast<const float4*>(src + i);
        ushort4 o;
        o.x = f2b(v.x); o.y = f2b(v.y); o.z = f2b(v.z); o.w = f2b(v.w);
        *reinterpret_cast<ushort4*>(dst + i) = o;
    }
}

// ---------------- GEMM 128x256 2-phase (round-13-verified: 116us, 0 conflicts) ----------------
template<int OUT_BF16>
__global__ __launch_bounds__(512) void gemm8p(const unsigned short* __restrict__ A,
                                              const unsigned short* __restrict__ Bw,
                                              void* __restrict__ Cout,
                                              int M, int N, int K) {
    __shared__ __align__(16) char lds[98304];   // [A0 16K][B0 32K][A1 16K][B1 32K]
    int tid = threadIdx.x;
    int lane = tid & 63;
    int wid = tid >> 6;
    int wm = wid >> 2, wn = wid & 3;
    int row0 = blockIdx.y * 128;
    int col0 = blockIdx.x * 256;
    int lr = lane & 15, g = lane >> 4;

    const unsigned short* srcA[2];
    const unsigned short* srcB[4];
#pragma unroll
    for (int i = 0; i < 2; i++) {
        int chunk = i * 512 + tid;
        int ksub = chunk >> 9;
        int cw = chunk & 511;
        int row = cw >> 2, c = cw & 3;
        int cs = c ^ ((row >> 1) & 3);
        srcA[i] = A + (size_t)(row0 + row) * K + ksub * 32 + cs * 8;
    }
#pragma unroll
    for (int i = 0; i < 4; i++) {
        int chunk = i * 512 + tid;
        int ksub = chunk >> 10;
        int cw = chunk & 1023;
        int row = cw >> 2, c = cw & 3;
        int cs = c ^ ((row >> 1) & 3);
        srcB[i] = Bw + (size_t)(col0 + row) * K + ksub * 32 + cs * 8;
    }

    int offA[4][2], offB[4][2];
#pragma unroll
    for (int i = 0; i < 4; i++) {
        int row = wm * 64 + i * 16 + lr;
#pragma unroll
        for (int ks = 0; ks < 2; ks++)
            offA[i][ks] = ks * 8192 + row * 64 + ((g ^ ((row >> 1) & 3)) * 16);
    }
#pragma unroll
    for (int j = 0; j < 4; j++) {
        int row = wn * 64 + j * 16 + lr;
#pragma unroll
        for (int ks = 0; ks < 2; ks++)
            offB[j][ks] = ks * 16384 + row * 64 + ((g ^ ((row >> 1) & 3)) * 16);
    }

    f32x4 acc[4][4] = {};
    int NT = K >> 6;

#define STAGE8(t) {                                                                   \
        int kb_ = (t) * 64;                                                           \
        int bs_ = ((t) & 1) * 49152;                                                  \
        _Pragma("unroll")                                                             \
        for (int i_ = 0; i_ < 2; i_++)                                                \
            gload_lds16(srcA[i_] + kb_,                                               \
                (unsigned short*)(lds + bs_ + (i_ * 512 + (tid & ~63)) * 16));        \
        _Pragma("unroll")                                                             \
        for (int i_ = 0; i_ < 4; i_++)                                                \
            gload_lds16(srcB[i_] + kb_,                                               \
                (unsigned short*)(lds + bs_ + 16384 + (i_ * 512 + (tid & ~63)) * 16)); \
    }

    STAGE8(0);
    for (int t = 0; t < NT; ++t) {
        if (t + 1 < NT) {
            STAGE8(t + 1);
            asm volatile("s_waitcnt vmcnt(6)" ::: "memory");
        } else {
            asm volatile("s_waitcnt vmcnt(0)" ::: "memory");
        }
        __builtin_amdgcn_s_barrier();
        __builtin_amdgcn_sched_barrier(0);

        const char* ab = lds + (t & 1) * 49152;
        const char* bb = ab + 16384;

        bf16x8 b[4][2], a[2][2];
#pragma unroll
        for (int j = 0; j < 4; j++)
#pragma unroll
            for (int ks = 0; ks < 2; ks++)
                b[j][ks] = *reinterpret_cast<const bf16x8*>(bb + offB[j][ks]);
#pragma unroll
        for (int i = 0; i < 2; i++)
#pragma unroll
            for (int ks = 0; ks < 2; ks++)
                a[i][ks] = *reinterpret_cast<const bf16x8*>(ab + offA[i][ks]);
        asm volatile("s_waitcnt lgkmcnt(0)" ::: "memory");
        __builtin_amdgcn_sched_barrier(0);
        __builtin_amdgcn_s_setprio(1);
#pragma unroll
        for (int ks = 0; ks < 2; ks++)
#pragma unroll
            for (int i = 0; i < 2; i++)
#pragma unroll
                for (int j = 0; j < 4; j++)
                    acc[i][j] = MFMA16(a[i][ks], b[j][ks], acc[i][j], 0, 0, 0);
        __builtin_amdgcn_s_setprio(0);

        bf16x8 a2[2][2];
#pragma unroll
        for (int i = 0; i < 2; i++)
#pragma unroll
            for (int ks = 0; ks < 2; ks++)
                a2[i][ks] = *reinterpret_cast<const bf16x8*>(ab + offA[2 + i][ks]);
        asm volatile("s_waitcnt lgkmcnt(0)" ::: "memory");
        __builtin_amdgcn_sched_barrier(0);
        __builtin_amdgcn_s_barrier();
        __builtin_amdgcn_sched_barrier(0);
        __builtin_amdgcn_s_setprio(1);
#pragma unroll
        for (int ks = 0; ks < 2; ks++)
#pragma unroll
            for (int i = 0; i < 2; i++)
#pragma unroll
                for (int j = 0; j < 4; j++)
                    acc[2 + i][j] = MFMA16(a2[i][ks], b[j][ks], acc[2 + i][j], 0, 0, 0);
        __builtin_amdgcn_s_setprio(0);
    }
#undef STAGE8

    int orow = g * 4;
#pragma unroll
    for (int i = 0; i < 4; i++) {
#pragma unroll
        for (int j = 0; j < 4; j++) {
            int r0 = row0 + wm * 64 + i * 16 + orow;
            int c  = col0 + wn * 64 + j * 16 + lr;
#pragma unroll
            for (int r = 0; r < 4; r++) {
                float v = acc[i][j][r];
                if (OUT_BF16)
                    ((unsigned short*)Cout)[(size_t)(r0 + r) * N + c] = f2b(v);
                else
                    ((float*)Cout)[(size_t)(r0 + r) * N + c] = v;
            }
        }
    }
}

// ---------------- RoPE + rearrange Q,K (Q pre-scaled by SM_SCALE*log2e) ----------------
__global__ void rope_qk(const unsigned short* __restrict__ qkv,
                        unsigned short* __restrict__ qb,
                        unsigned short* __restrict__ kb) {
    int idx = blockIdx.x * 256 + threadIdx.x;
    int i = idx & 63;
    int h = (idx >> 6) & 15;
    int t = idx >> 10;
    int s = t & (SEQ - 1);
    int b = t >> 11;

    float inv = exp2f(-13.287712379549449f * (float)i * (1.0f / 64.0f));
    float ang = (float)s * inv;
    float sn, cs;
    sincosf(ang, &sn, &cs);

    const unsigned short* base = qkv + (size_t)t * 6144 + h * 128 + 2 * i;
    unsigned qv = *reinterpret_cast<const unsigned*>(base);
    unsigned kv = *reinterpret_cast<const unsigned*>(base + 2048);

    float qe = b2f((unsigned short)(qv & 0xFFFF));
    float qo = b2f((unsigned short)(qv >> 16));
    float ke = b2f((unsigned short)(kv & 0xFFFF));
    float ko = b2f((unsigned short)(kv >> 16));

    float qe2 = (qe * cs - qo * sn) * QSCALE;
    float qo2 = (qe * sn + qo * cs) * QSCALE;
    float ke2 = ke * cs - ko * sn;
    float ko2 = ke * sn + ko * cs;

    size_t o = ((size_t)(b * NH + h) * SEQ + s) * HD + 2 * i;
    *reinterpret_cast<unsigned*>(qb + o) = (unsigned)f2b(qe2) | ((unsigned)f2b(qo2) << 16);
    *reinterpret_cast<unsigned*>(kb + o) = (unsigned)f2b(ke2) | ((unsigned)f2b(ko2) << 16);
}

// ---------------- V rearrange: qkv -> vt [B][H][HD][S] ----------------
__global__ void v_rearr(const unsigned short* __restrict__ qkv, unsigned short* __restrict__ vt) {
    int idx = blockIdx.x * 256 + threadIdx.x;
    int s4 = (idx & 511) * 4;
    int d  = (idx >> 9) & 127;
    int h  = (idx >> 16) & 15;
    int b  = idx >> 20;
    ushort4 o;
    size_t rbase = (size_t)(b * SEQ + s4) * 6144 + 4096 + h * 128 + d;
    o.x = qkv[rbase];
    o.y = qkv[rbase + 6144];
    o.z = qkv[rbase + 2 * 6144];
    o.w = qkv[rbase + 3 * 6144];
    *reinterpret_cast<ushort4*>(vt + ((size_t)(b * NH + h) * HD + d) * SEQ + s4) = o;
}

// ---------------- flash attention v7: split-K across 2 waves/block ----------------
// Block = one 32-row q-tile (heavy-first order). Wave w does KV tiles t = w, w+2, ...
// Private per-wave single K buffer (16KB, gload_lds staged, pre-swizzled source) +
// private P (4KB) -> 40KB LDS, 4 blocks/CU = 2 waves/SIMD, no in-loop inter-wave sync.
// Partial (m,l,O) merged through LDS at the end.
__global__ __launch_bounds__(128, 1) void attn7(const unsigned short* __restrict__ Q,
                                                const unsigned short* __restrict__ Kb,
                                                const unsigned short* __restrict__ Vt,
                                                unsigned short* __restrict__ O) {
    __shared__ __align__(16) char lds[40960];   // [0:16K) K w0 | [16K:32K) K w1 | [32K:36K) P w0 | [36K:40K) P w1

    int tid = threadIdx.x;
    int lane = tid & 63;
    int w = tid >> 6;
    int bid = blockIdx.x;
    int qt = 63 - (bid >> 5);       // heavy blocks first (LPT scheduling)
    int bh = bid & 31;              // bid%8 == bh%8 -> head->XCD affinity
    int q0 = qt * 32;
    int ktiles = (qt >> 1) + 1;
    int lr = lane & 15;
    int g  = lane >> 4;
    int g4 = g * 4;
    int lk = g * 8;

    const unsigned short* Qp = Q  + (size_t)bh * SEQ * HD;
    const unsigned short* Kp = Kb + (size_t)bh * SEQ * HD;
    const unsigned short* Vp = Vt + (size_t)bh * HD * SEQ;
    char* kl = lds + w * 16384;
    char* pl = lds + 32768 + w * 4096;
    int b = bh >> 4;
    int h = bh & 15;

    int srcoff[16];
#pragma unroll
    for (int i2 = 0; i2 < 16; ++i2) {
        int r = i2 * 4 + g;
        srcoff[i2] = r * HD + ((lr ^ (r & 7)) * 8);
    }

#define STAGEK7(kvbase) {                                                           \
        const unsigned short* kbase = Kp + (size_t)(kvbase) * HD;                   \
        _Pragma("unroll")                                                           \
        for (int i2 = 0; i2 < 16; ++i2)                                             \
            gload_lds16(kbase + srcoff[i2],                                         \
                        (unsigned short*)(kl + i2 * 1024));                         \
    }

    bf16x8 qf[2][4];
#pragma unroll
    for (int f = 0; f < 2; f++)
#pragma unroll
        for (int kb = 0; kb < 4; kb++)
            qf[f][kb] = *reinterpret_cast<const bf16x8*>(Qp + (size_t)(q0 + f * 16 + lr) * HD + kb * 32 + lk);

    f32x4 oacc[2][8] = {};
    float m[2] = { -1e30f, -1e30f }, l[2] = { 0.0f, 0.0f };
    int qrow[2] = { q0 + lr, q0 + 16 + lr };

    if (w < ktiles) STAGEK7(w * 64);

    for (int t = w; t < ktiles; t += 2) {
        int kv0 = t * 64;
        asm volatile("s_waitcnt vmcnt(0)" ::: "memory");   // this wave's K tile landed
        __builtin_amdgcn_sched_barrier(0);

        // ---- QK^T swapped: lane owns q = lane&15, 16 in-lane kv scores ----
        f32x4 s[2][4] = {};
#pragma unroll
        for (int kb = 0; kb < 4; kb++) {
#pragma unroll
            for (int jj = 0; jj < 4; jj++) {
                int row = jj * 16 + lr;
                int cin = ((kb * 4 + g) ^ (row & 7));
                bf16x8 kf = *reinterpret_cast<const bf16x8*>(kl + row * 256 + cin * 16);
                s[0][jj] = MFMA16(kf, qf[0][kb], s[0][jj], 0, 0, 0);
                s[1][jj] = MFMA16(kf, qf[1][kb], s[1][jj], 0, 0, 0);
            }
        }

        // ---- V prefetch (issue early, consumed at PV) ----
        bf16x8 vf[8][2];
#pragma unroll
        for (int db = 0; db < 8; db++)
#pragma unroll
            for (int ks = 0; ks < 2; ks++)
                vf[db][ks] = *reinterpret_cast<const bf16x8*>(Vp + (size_t)(db * 16 + lr) * SEQ + kv0 + ks * 32 + lk);

        // ---- in-lane online softmax (exp2 domain, defer-max) ----
#pragma unroll
        for (int f = 0; f < 2; f++) {
            int q = qrow[f];
            bool full = (kv0 + 63 <= q0 + f * 16);
            float mx = -1e30f;
            if (full) {
#pragma unroll
                for (int jj = 0; jj < 4; jj++)
#pragma unroll
                    for (int r = 0; r < 4; r++)
                        mx = fmaxf(mx, s[f][jj][r]);
            } else {
#pragma unroll
                for (int jj = 0; jj < 4; jj++)
#pragma unroll
                    for (int r = 0; r < 4; r++) {
                        int kv = kv0 + jj * 16 + g4 + r;
                        float v = (kv <= q) ? s[f][jj][r] : -1e30f;
                        s[f][jj][r] = v;
                        mx = fmaxf(mx, v);
                    }
            }
            mx = fmaxf(mx, __shfl_xor(mx, 16));
            mx = fmaxf(mx, __shfl_xor(mx, 32));

            if (!__all(mx <= m[f] + THRL2)) {
                float mn = fmaxf(m[f], mx);
                float sc = fexp2(m[f] - mn);
                m[f] = mn;
                l[f] *= sc;
#pragma unroll
                for (int db = 0; db < 8; db++)
#pragma unroll
                    for (int r = 0; r < 4; r++)
                        oacc[f][db][r] *= sc;
            }

            int row = f * 16 + lr;
            int rb = row * 128;
            int sw = (row & 7) << 4;
            float rs = 0.0f;
#pragma unroll
            for (int jj = 0; jj < 4; jj++)
#pragma unroll
                for (int hh = 0; hh < 2; hh++) {
                    float p0 = fexp2(s[f][jj][2 * hh]     - m[f]);
                    float p1 = fexp2(s[f][jj][2 * hh + 1] - m[f]);
                    rs += p0 + p1;
                    unsigned pk = cvtpk(p0, p1);
                    int colb = jj * 32 + g * 8 + 4 * hh;
                    *reinterpret_cast<unsigned*>(pl + rb + (colb ^ sw)) = pk;
                }
            rs += __shfl_xor(rs, 16);
            rs += __shfl_xor(rs, 32);
            l[f] += rs;
        }

        asm volatile("s_waitcnt lgkmcnt(0)" ::: "memory");  // K ds_reads + P writes drained
        __builtin_amdgcn_sched_barrier(0);

        // stage this wave's NEXT tile into the same buffer (WAR-safe: reads drained)
        if (t + 2 < ktiles) STAGEK7((t + 2) * 64);

        // ---- P fragments + swapped PV ----
        bf16x8 pb[2][2];
#pragma unroll
        for (int f = 0; f < 2; f++)
#pragma unroll
            for (int ks = 0; ks < 2; ks++) {
                int row = f * 16 + lr;
                int off = row * 128 + ((ks * 64 + g * 16) ^ ((row & 7) << 4));
                pb[f][ks] = *reinterpret_cast<const bf16x8*>(pl + off);
            }
#pragma unroll
        for (int db = 0; db < 8; db++)
#pragma unroll
            for (int ks = 0; ks < 2; ks++) {
                oacc[0][db] = MFMA16(vf[db][ks], pb[0][ks], oacc[0][db], 0, 0, 0);
                oacc[1][db] = MFMA16(vf[db][ks], pb[1][ks], oacc[1][db], 0, 0, 0);
            }
    }
#undef STAGEK7

    // ---- merge partials: wave1 -> LDS, wave0 combines + stores ----
    __syncthreads();                 // both waves done with K buffers
    if (w == 1) {
#pragma unroll
        for (int f = 0; f < 2; f++) {
#pragma unroll
            for (int db = 0; db < 8; db++)
                *reinterpret_cast<f32x4*>(lds + ((f * 8 + db) * 64 + lane) * 16) = oacc[f][db];
            *reinterpret_cast<float2*>(lds + 16384 + (f * 64 + lane) * 8) = make_float2(m[f], l[f]);
        }
    }
    __syncthreads();
    if (w == 0) {
#pragma unroll
        for (int f = 0; f < 2; f++) {
            float2 ml1 = *reinterpret_cast<const float2*>(lds + 16384 + (f * 64 + lane) * 8);
            float mt = fmaxf(m[f], ml1.x);
            float sc0 = fexp2(m[f] - mt);
            float sc1 = fexp2(ml1.x - mt);
            float L = l[f] * sc0 + ml1.y * sc1;
            float inv = 1.0f / L;
            int q = q0 + f * 16 + lr;
            unsigned short* op = O + ((size_t)(b * SEQ + q)) * DMODEL + h * HD;
#pragma unroll
            for (int db = 0; db < 8; db++) {
                f32x4 o1 = *reinterpret_cast<const f32x4*>(lds + ((f * 8 + db) * 64 + lane) * 16);
                ushort4 o4;
                o4.x = f2b((oacc[f][db][0] * sc0 + o1[0] * sc1) * inv);
                o4.y = f2b((oacc[f][db][1] * sc0 + o1[1] * sc1) * inv);
                o4.z = f2b((oacc[f][db][2] * sc0 + o1[2] * sc1) * inv);
                o4.w = f2b((oacc[f][db][3] * sc0 + o1[3] * sc1) * inv);
                *reinterpret_cast<ushort4*>(op + db * 16 + g4) = o4;
            }
        }
    }
}

extern "C" void kernel_launch(void* const* d_in, const int* in_sizes, int n_in,
                              void* d_out, int out_size, void* d_ws, size_t ws_size,
                              hipStream_t stream) {
    const float* x   = (const float*)d_in[0];
    const float* wqk = (const float*)d_in[1];
    const float* wv  = (const float*)d_in[2];
    const float* wo  = (const float*)d_in[3];

    unsigned short* xb  = (unsigned short*)d_ws;            // [4096][2048]
    unsigned short* wb  = xb  + (size_t)8388608;            // [8192][2048]: wqk | wv | wo
    unsigned short* qkv = wb  + (size_t)16777216;           // [4096][6144]
    unsigned short* qb  = qkv + (size_t)25165824;           // [B][H][S][HD]
    unsigned short* kb  = qb  + (size_t)8388608;
    unsigned short* vt  = kb  + (size_t)8388608;            // [B][H][HD][S]
    unsigned short* ao  = vt  + (size_t)8388608;            // [4096][2048]

    cast_f2b<<<8192, 256, 0, stream>>>(x,   xb, 8388608);
    cast_f2b<<<8192, 256, 0, stream>>>(wqk, wb, 8388608);
    cast_f2b<<<4096, 256, 0, stream>>>(wv,  wb + 8388608, 4194304);
    cast_f2b<<<4096, 256, 0, stream>>>(wo,  wb + 12582912, 4194304);

    // QKV projection: round-13-verified 2-phase kernel (768 blocks = 3 exact CU rounds)
    gemm8p<1><<<dim3(24, 32), 512, 0, stream>>>(xb, wb, (void*)qkv, 4096, 6144, 2048);

    rope_qk<<<16384, 256, 0, stream>>>(qkv, qb, kb);
    v_rearr<<<8192, 256, 0, stream>>>(qkv, vt);

    // split-K attention: 2048 blocks x 128 thr (2 waves), heavy-first
    attn7<<<2048, 128, 0, stream>>>(qb, kb, vt, ao);

    // out projection: 256 blocks = 1 exact CU round
    gemm8p<0><<<dim3(8, 32), 512, 0, stream>>>(ao, wb + 12582912, d_out, 4096, 2048, 2048);
}

// Round 16
// 283.216 us; speedup vs baseline: 1.1721x; 1.1518x over previous
//
#include <hip/hip_runtime.h>
#include <hip/hip_bf16.h>

#define NB 2
#define SEQ 2048
#define DMODEL 2048
#define NH 16
#define HD 128
// SM_SCALE * log2(e): softmax computed in exp2 domain
#define QSCALE (0.08838834764831845f * 1.44269504088896f)
#define THRL2 11.5f

using bf16x8 = __attribute__((ext_vector_type(8))) __bf16;
using f32x4  = __attribute__((ext_vector_type(4))) float;

#define MFMA16 __builtin_amdgcn_mfma_f32_16x16x32_bf16

typedef __attribute__((address_space(1))) const void* gptr_t;
typedef __attribute__((address_space(3))) void* lptr_t;

__device__ inline void gload_lds16(const unsigned short* g, unsigned short* l) {
    __builtin_amdgcn_global_load_lds((gptr_t)g, (lptr_t)l, 16, 0, 0);
}

__device__ inline unsigned short f2b(float f) {
    unsigned u = __builtin_bit_cast(unsigned, f);
    u += 0x7FFF + ((u >> 16) & 1);
    return (unsigned short)(u >> 16);
}
__device__ inline float b2f(unsigned short h) {
    return __builtin_bit_cast(float, (unsigned)h << 16);
}
__device__ inline float fexp2(float x) {
    float r;
    asm("v_exp_f32 %0, %1" : "=v"(r) : "v"(x));
    return r;
}
__device__ inline unsigned cvtpk(float a, float b) {   // low=bf16(a), high=bf16(b)
    unsigned r;
    asm("v_cvt_pk_bf16_f32 %0, %1, %2" : "=v"(r) : "v"(a), "v"(b));
    return r;
}

// ---------------- cast fp32 -> bf16, 4 elems/thread ----------------
__global__ void cast_f2b(const float* __restrict__ src, unsigned short* __restrict__ dst, int n) {
    int i = (blockIdx.x * 256 + threadIdx.x) * 4;
    if (i + 3 < n) {
        float4 v = *reinterpret_cast<const float4*>(src + i);
        ushort4 o;
        o.x = f2b(v.x); o.y = f2b(v.y); o.z = f2b(v.z); o.w = f2b(v.w);
        *reinterpret_cast<ushort4*>(dst + i) = o;
    }
}

// ---------------- RoPE cos/sin table: tab[s][i] = (cos, sin) of s * 10000^(-i/64) ----------------
__global__ void rope_tab(float2* __restrict__ tab) {
    int idx = blockIdx.x * 256 + threadIdx.x;   // 2048*64
    int i = idx & 63;
    int s = idx >> 6;
    float inv = exp2f(-13.287712379549449f * (float)i * (1.0f / 64.0f));
    float ang = (float)s * inv;
    float sn, cs;
    sincosf(ang, &sn, &cs);
    tab[idx] = make_float2(cs, sn);
}

// ======== GEMM 128x256 2-phase core (r13-verified: 0 conflicts, counted vmcnt) ========
// MODE 0: fp32 C write. MODE 2: fused QKV epilogue (bx<8 Q-rope->qb, 8..15 K-rope->kb,
// 16..23 plain->vx).
template<int MODE>
__global__ __launch_bounds__(512) void gemm8p(const unsigned short* __restrict__ A,
                                              const unsigned short* __restrict__ Bw,
                                              void* __restrict__ Cout,
                                              unsigned short* __restrict__ qb,
                                              unsigned short* __restrict__ kbp,
                                              unsigned short* __restrict__ vx,
                                              const float2* __restrict__ tab,
                                              int M, int N, int K) {
    __shared__ __align__(16) char lds[98304];   // [A0 16K][B0 32K][A1 16K][B1 32K]
    int tid = threadIdx.x;
    int lane = tid & 63;
    int wid = tid >> 6;
    int wm = wid >> 2, wn = wid & 3;
    int row0 = blockIdx.y * 128;
    int col0 = blockIdx.x * 256;
    int lr = lane & 15, g = lane >> 4;

    const unsigned short* srcA[2];
    const unsigned short* srcB[4];
#pragma unroll
    for (int i = 0; i < 2; i++) {
        int chunk = i * 512 + tid;
        int ksub = chunk >> 9;
        int cw = chunk & 511;
        int row = cw >> 2, c = cw & 3;
        int cs = c ^ ((row >> 1) & 3);
        srcA[i] = A + (size_t)(row0 + row) * K + ksub * 32 + cs * 8;
    }
#pragma unroll
    for (int i = 0; i < 4; i++) {
        int chunk = i * 512 + tid;
        int ksub = chunk >> 10;
        int cw = chunk & 1023;
        int row = cw >> 2, c = cw & 3;
        int cs = c ^ ((row >> 1) & 3);
        srcB[i] = Bw + (size_t)(col0 + row) * K + ksub * 32 + cs * 8;
    }

    int offA[4][2], offB[4][2];
#pragma unroll
    for (int i = 0; i < 4; i++) {
        int row = wm * 64 + i * 16 + lr;
#pragma unroll
        for (int ks = 0; ks < 2; ks++)
            offA[i][ks] = ks * 8192 + row * 64 + ((g ^ ((row >> 1) & 3)) * 16);
    }
#pragma unroll
    for (int j = 0; j < 4; j++) {
        int row = wn * 64 + j * 16 + lr;
#pragma unroll
        for (int ks = 0; ks < 2; ks++)
            offB[j][ks] = ks * 16384 + row * 64 + ((g ^ ((row >> 1) & 3)) * 16);
    }

    f32x4 acc[4][4] = {};
    int NT = K >> 6;

#define STAGE8(t) {                                                                   \
        int kb_ = (t) * 64;                                                           \
        int bs_ = ((t) & 1) * 49152;                                                  \
        _Pragma("unroll")                                                             \
        for (int i_ = 0; i_ < 2; i_++)                                                \
            gload_lds16(srcA[i_] + kb_,                                               \
                (unsigned short*)(lds + bs_ + (i_ * 512 + (tid & ~63)) * 16));        \
        _Pragma("unroll")                                                             \
        for (int i_ = 0; i_ < 4; i_++)                                                \
            gload_lds16(srcB[i_] + kb_,                                               \
                (unsigned short*)(lds + bs_ + 16384 + (i_ * 512 + (tid & ~63)) * 16)); \
    }

    STAGE8(0);
    for (int t = 0; t < NT; ++t) {
        if (t + 1 < NT) {
            STAGE8(t + 1);
            asm volatile("s_waitcnt vmcnt(6)" ::: "memory");
        } else {
            asm volatile("s_waitcnt vmcnt(0)" ::: "memory");
        }
        __builtin_amdgcn_s_barrier();
        __builtin_amdgcn_sched_barrier(0);

        const char* ab = lds + (t & 1) * 49152;
        const char* bb = ab + 16384;

        bf16x8 b[4][2], a[2][2];
#pragma unroll
        for (int j = 0; j < 4; j++)
#pragma unroll
            for (int ks = 0; ks < 2; ks++)
                b[j][ks] = *reinterpret_cast<const bf16x8*>(bb + offB[j][ks]);
#pragma unroll
        for (int i = 0; i < 2; i++)
#pragma unroll
            for (int ks = 0; ks < 2; ks++)
                a[i][ks] = *reinterpret_cast<const bf16x8*>(ab + offA[i][ks]);
        asm volatile("s_waitcnt lgkmcnt(0)" ::: "memory");
        __builtin_amdgcn_sched_barrier(0);
        __builtin_amdgcn_s_setprio(1);
#pragma unroll
        for (int ks = 0; ks < 2; ks++)
#pragma unroll
            for (int i = 0; i < 2; i++)
#pragma unroll
                for (int j = 0; j < 4; j++)
                    acc[i][j] = MFMA16(a[i][ks], b[j][ks], acc[i][j], 0, 0, 0);
        __builtin_amdgcn_s_setprio(0);

        bf16x8 a2[2][2];
#pragma unroll
        for (int i = 0; i < 2; i++)
#pragma unroll
            for (int ks = 0; ks < 2; ks++)
                a2[i][ks] = *reinterpret_cast<const bf16x8*>(ab + offA[2 + i][ks]);
        asm volatile("s_waitcnt lgkmcnt(0)" ::: "memory");
        __builtin_amdgcn_sched_barrier(0);
        __builtin_amdgcn_s_barrier();
        __builtin_amdgcn_sched_barrier(0);
        __builtin_amdgcn_s_setprio(1);
#pragma unroll
        for (int ks = 0; ks < 2; ks++)
#pragma unroll
            for (int i = 0; i < 2; i++)
#pragma unroll
                for (int j = 0; j < 4; j++)
                    acc[2 + i][j] = MFMA16(a2[i][ks], b[j][ks], acc[2 + i][j], 0, 0, 0);
        __builtin_amdgcn_s_setprio(0);
    }
#undef STAGE8

    int orow = g * 4;
    if (MODE == 0) {
#pragma unroll
        for (int i = 0; i < 4; i++) {
#pragma unroll
            for (int j = 0; j < 4; j++) {
                int r0 = row0 + wm * 64 + i * 16 + orow;
                int c  = col0 + wn * 64 + j * 16 + lr;
#pragma unroll
                for (int r = 0; r < 4; r++)
                    ((float*)Cout)[(size_t)(r0 + r) * N + c] = acc[i][j][r];
            }
        }
    } else {
        int bx = blockIdx.x;
        if (bx < 16) {
            const bool isQ = (bx < 8);
            unsigned short* dst = isQ ? qb : kbp;
#pragma unroll
            for (int i = 0; i < 4; i++) {
#pragma unroll
                for (int j = 0; j < 4; j++) {
                    int c = col0 + wn * 64 + j * 16 + lr;
                    int cc = c & 2047;
                    int h = cc >> 7, d = cc & 127, i2 = d >> 1;
                    int odd = lr & 1;
#pragma unroll
                    for (int r = 0; r < 4; r++) {
                        int trow = row0 + wm * 64 + i * 16 + orow + r;
                        int s = trow & (SEQ - 1), bb2 = trow >> 11;
                        float v = acc[i][j][r];
                        float pv = __shfl_xor(v, 1);
                        float2 cssn = tab[s * 64 + i2];
                        // even d: xe*cos - xo*sin ; odd d: xe*sin + xo*cos
                        float out = odd ? (pv * cssn.y + v * cssn.x)
                                        : (v * cssn.x - pv * cssn.y);
                        if (isQ) out *= QSCALE;
                        dst[((size_t)((bb2 * NH + h) * SEQ + s)) * HD + d] = f2b(out);
                    }
                }
            }
        } else {
#pragma unroll
            for (int i = 0; i < 4; i++) {
#pragma unroll
                for (int j = 0; j < 4; j++) {
                    int cc = col0 + wn * 64 + j * 16 + lr - 4096;
#pragma unroll
                    for (int r = 0; r < 4; r++) {
                        int trow = row0 + wm * 64 + i * 16 + orow + r;
                        vx[(size_t)trow * 2048 + cc] = f2b(acc[i][j][r]);
                    }
                }
            }
        }
    }
}

// ---------------- V transpose: vx[4096][2048] -> vt [bh][d][s], LDS-tiled 64x64 ----------------
__global__ __launch_bounds__(256) void v_tr(const unsigned short* __restrict__ vx,
                                            unsigned short* __restrict__ vt) {
    __shared__ unsigned short tl[64][68];   // 68-stride: 8B-aligned rows, 2-way-free cols
    int bid = blockIdx.x;                   // 32 st x 2 dt x 32 bh = 2048
    int st = bid & 31;
    int dt = (bid >> 5) & 1;
    int bh = bid >> 6;
    int b = bh >> 4, h = bh & 15;
    int tid = threadIdx.x;
    int rr = tid >> 2;
    int rc = (tid & 3) * 16;

    // read 64 rows (s) x 64 cols (d), coalesced 16B
    const unsigned short* src = vx + (size_t)(b * SEQ + st * 64 + rr) * 2048 + h * HD + dt * 64 + rc;
    uint4 v0 = *reinterpret_cast<const uint4*>(src);
    uint4 v1 = *reinterpret_cast<const uint4*>(src + 8);
    *reinterpret_cast<uint4*>(&tl[rr][rc]) = v0;       // 68-stride rows are 8B-aligned; compiler splits to b64
    *reinterpret_cast<uint4*>(&tl[rr][rc + 8]) = v1;
    __syncthreads();

    // write: vt row = bh*128 + dt*64 + rr, cols s = st*64 + rc .. +15
    unsigned short tmp[16];
#pragma unroll
    for (int k = 0; k < 16; k++) tmp[k] = tl[rc + k][rr];
    unsigned short* dst = vt + (size_t)(bh * HD + dt * 64 + rr) * SEQ + st * 64 + rc;
    *reinterpret_cast<uint4*>(dst)     = *reinterpret_cast<const uint4*>(&tmp[0]);
    *reinterpret_cast<uint4*>(dst + 8) = *reinterpret_cast<const uint4*>(&tmp[8]);
}

// ---------------- flash attention v6 (r13-verified, ~100us) ----------------
__global__ __launch_bounds__(64, 1) void attn6(const unsigned short* __restrict__ Q,
                                               const unsigned short* __restrict__ Kb,
                                               const unsigned short* __restrict__ Vt,
                                               unsigned short* __restrict__ O) {
    __shared__ __align__(16) char lds[36864];   // 2x16KB K dbuf + 4KB P

    int lane = threadIdx.x;
    int bid = blockIdx.x;
    int p  = bid >> 5;
    int bh = bid & 31;
    int lr = lane & 15;
    int g  = lane >> 4;
    int g4 = g * 4;
    int lk = g * 8;

    const unsigned short* Qp = Q  + (size_t)bh * SEQ * HD;
    const unsigned short* Kp = Kb + (size_t)bh * SEQ * HD;
    const unsigned short* Vp = Vt + (size_t)bh * HD * SEQ;
    char* pl = lds + 32768;
    int b = bh >> 4;
    int h = bh & 15;

    int srcoff[16];
#pragma unroll
    for (int i2 = 0; i2 < 16; ++i2) {
        int r = i2 * 4 + g;
        srcoff[i2] = r * HD + ((lr ^ (r & 7)) * 8);
    }

#define STAGEK(bufbase, kvbase)                                                     \
    {                                                                               \
        const unsigned short* kbase = Kp + (size_t)(kvbase) * HD;                   \
        _Pragma("unroll")                                                           \
        for (int i2 = 0; i2 < 16; ++i2)                                             \
            gload_lds16(kbase + srcoff[i2],                                         \
                        (unsigned short*)(lds + (bufbase) + i2 * 1024));            \
    }

    for (int ph = 0; ph < 2; ++ph) {
        int j  = ph ? (63 - p) : p;
        int q0 = j * 32;
        int ktiles = (j >> 1) + 1;

        bf16x8 qf[2][4];
#pragma unroll
        for (int f = 0; f < 2; f++)
#pragma unroll
            for (int kb = 0; kb < 4; kb++)
                qf[f][kb] = *reinterpret_cast<const bf16x8*>(Qp + (size_t)(q0 + f * 16 + lr) * HD + kb * 32 + lk);

        f32x4 oacc[2][8] = {};
        float m[2] = { -1e30f, -1e30f }, l[2] = { 0.0f, 0.0f };
        int qrow[2] = { q0 + lr, q0 + 16 + lr };

        STAGEK(0, 0);

        int cur = 0;
        for (int t = 0; t < ktiles; ++t) {
            int kv0 = t * 64;
            if (t + 1 < ktiles) {
                STAGEK((cur ^ 1) * 16384, kv0 + 64);
                asm volatile("s_waitcnt vmcnt(16)" ::: "memory");
            } else {
                asm volatile("s_waitcnt vmcnt(0)" ::: "memory");
            }
            __builtin_amdgcn_sched_barrier(0);

            char* kb_c = lds + cur * 16384;
            f32x4 s[2][4] = {};
#pragma unroll
            for (int kb = 0; kb < 4; kb++) {
#pragma unroll
                for (int jj = 0; jj < 4; jj++) {
                    int row = jj * 16 + lr;
                    int cin = ((kb * 4 + g) ^ (row & 7));
                    bf16x8 kf = *reinterpret_cast<const bf16x8*>(kb_c + row * 256 + cin * 16);
                    s[0][jj] = MFMA16(kf, qf[0][kb], s[0][jj], 0, 0, 0);
                    s[1][jj] = MFMA16(kf, qf[1][kb], s[1][jj], 0, 0, 0);
                }
            }

            bf16x8 vf[8][2];
#pragma unroll
            for (int db = 0; db < 8; db++)
#pragma unroll
                for (int ks = 0; ks < 2; ks++)
                    vf[db][ks] = *reinterpret_cast<const bf16x8*>(Vp + (size_t)(db * 16 + lr) * SEQ + kv0 + ks * 32 + lk);

#pragma unroll
            for (int f = 0; f < 2; f++) {
                int q = qrow[f];
                bool full = (kv0 + 63 <= q0 + f * 16);
                float mx = -1e30f;
                if (full) {
#pragma unroll
                    for (int jj = 0; jj < 4; jj++)
#pragma unroll
                        for (int r = 0; r < 4; r++)
                            mx = fmaxf(mx, s[f][jj][r]);
                } else {
#pragma unroll
                    for (int jj = 0; jj < 4; jj++)
#pragma unroll
                        for (int r = 0; r < 4; r++) {
                            int kv = kv0 + jj * 16 + g4 + r;
                            float v = (kv <= q) ? s[f][jj][r] : -1e30f;
                            s[f][jj][r] = v;
                            mx = fmaxf(mx, v);
                        }
                }
                mx = fmaxf(mx, __shfl_xor(mx, 16));
                mx = fmaxf(mx, __shfl_xor(mx, 32));

                if (!__all(mx <= m[f] + THRL2)) {
                    float mn = fmaxf(m[f], mx);
                    float sc = fexp2(m[f] - mn);
                    m[f] = mn;
                    l[f] *= sc;
#pragma unroll
                    for (int db = 0; db < 8; db++)
#pragma unroll
                        for (int r = 0; r < 4; r++)
                            oacc[f][db][r] *= sc;
                }

                int row = f * 16 + lr;
                int rb = row * 128;
                int sw = (row & 7) << 4;
                float rs = 0.0f;
#pragma unroll
                for (int jj = 0; jj < 4; jj++)
#pragma unroll
                    for (int hh = 0; hh < 2; hh++) {
                        float p0 = fexp2(s[f][jj][2 * hh]     - m[f]);
                        float p1 = fexp2(s[f][jj][2 * hh + 1] - m[f]);
                        rs += p0 + p1;
                        unsigned pk = cvtpk(p0, p1);
                        int colb = jj * 32 + g * 8 + 4 * hh;
                        *reinterpret_cast<unsigned*>(pl + rb + (colb ^ sw)) = pk;
                    }
                rs += __shfl_xor(rs, 16);
                rs += __shfl_xor(rs, 32);
                l[f] += rs;
            }

            asm volatile("s_waitcnt lgkmcnt(0)" ::: "memory");
            __builtin_amdgcn_sched_barrier(0);

            bf16x8 pb[2][2];
#pragma unroll
            for (int f = 0; f < 2; f++)
#pragma unroll
                for (int ks = 0; ks < 2; ks++) {
                    int row = f * 16 + lr;
                    int off = row * 128 + ((ks * 64 + g * 16) ^ ((row & 7) << 4));
                    pb[f][ks] = *reinterpret_cast<const bf16x8*>(pl + off);
                }
#pragma unroll
            for (int db = 0; db < 8; db++)
#pragma unroll
                for (int ks = 0; ks < 2; ks++) {
                    oacc[0][db] = MFMA16(vf[db][ks], pb[0][ks], oacc[0][db], 0, 0, 0);
                    oacc[1][db] = MFMA16(vf[db][ks], pb[1][ks], oacc[1][db], 0, 0, 0);
                }

            cur ^= 1;
        }

#pragma unroll
        for (int f = 0; f < 2; f++) {
            float inv = 1.0f / l[f];
            int q = q0 + f * 16 + lr;
            unsigned short* op = O + ((size_t)(b * SEQ + q)) * DMODEL + h * HD;
#pragma unroll
            for (int db = 0; db < 8; db++) {
                ushort4 o4;
                o4.x = f2b(oacc[f][db][0] * inv);
                o4.y = f2b(oacc[f][db][1] * inv);
                o4.z = f2b(oacc[f][db][2] * inv);
                o4.w = f2b(oacc[f][db][3] * inv);
                *reinterpret_cast<ushort4*>(op + db * 16 + g4) = o4;
            }
        }
    }
#undef STAGEK
}

extern "C" void kernel_launch(void* const* d_in, const int* in_sizes, int n_in,
                              void* d_out, int out_size, void* d_ws, size_t ws_size,
                              hipStream_t stream) {
    const float* x   = (const float*)d_in[0];
    const float* wqk = (const float*)d_in[1];
    const float* wv  = (const float*)d_in[2];
    const float* wo  = (const float*)d_in[3];

    unsigned short* xb  = (unsigned short*)d_ws;            // [4096][2048]
    unsigned short* wb  = xb  + (size_t)8388608;            // [8192][2048]: wqk | wv | wo
    unsigned short* qb  = wb  + (size_t)16777216;           // [B][H][S][HD]
    unsigned short* kb  = qb  + (size_t)8388608;
    unsigned short* vx  = kb  + (size_t)8388608;            // [4096][2048] plain V
    unsigned short* vt  = vx  + (size_t)8388608;            // [B][H][HD][S]
    unsigned short* ao  = vt  + (size_t)8388608;            // [4096][2048]
    float2* tab = (float2*)(ao + (size_t)8388608);          // [2048][64]

    cast_f2b<<<8192, 256, 0, stream>>>(x,   xb, 8388608);
    cast_f2b<<<8192, 256, 0, stream>>>(wqk, wb, 8388608);
    cast_f2b<<<4096, 256, 0, stream>>>(wv,  wb + 8388608, 4194304);
    cast_f2b<<<4096, 256, 0, stream>>>(wo,  wb + 12582912, 4194304);
    rope_tab<<<512, 256, 0, stream>>>(tab);

    // fused QKV projection + RoPE + layout: writes qb, kb, vx directly
    gemm8p<2><<<dim3(24, 32), 512, 0, stream>>>(xb, wb, nullptr, qb, kb, vx, tab, 4096, 6144, 2048);

    v_tr<<<2048, 256, 0, stream>>>(vx, vt);

    attn6<<<1024, 64, 0, stream>>>(qb, kb, vt, ao);

    // out projection
    gemm8p<0><<<dim3(8, 32), 512, 0, stream>>>(ao, wb + 12582912, d_out, nullptr, nullptr, nullptr, nullptr, 4096, 2048, 2048);
}

// Round 17
// 279.483 us; speedup vs baseline: 1.1878x; 1.0134x over previous
//
#include <hip/hip_runtime.h>
#include <hip/hip_bf16.h>

#define NB 2
#define SEQ 2048
#define DMODEL 2048
#define NH 16
#define HD 128
// SM_SCALE * log2(e): softmax computed in exp2 domain
#define QSCALE (0.08838834764831845f * 1.44269504088896f)
#define THRL2 11.5f

using bf16x8 = __attribute__((ext_vector_type(8))) __bf16;
using f32x4  = __attribute__((ext_vector_type(4))) float;

#define MFMA16 __builtin_amdgcn_mfma_f32_16x16x32_bf16

typedef __attribute__((address_space(1))) const void* gptr_t;
typedef __attribute__((address_space(3))) void* lptr_t;

__device__ inline void gload_lds16(const unsigned short* g, unsigned short* l) {
    __builtin_amdgcn_global_load_lds((gptr_t)g, (lptr_t)l, 16, 0, 0);
}

__device__ inline unsigned short f2b(float f) {
    unsigned u = __builtin_bit_cast(unsigned, f);
    u += 0x7FFF + ((u >> 16) & 1);
    return (unsigned short)(u >> 16);
}
__device__ inline float b2f(unsigned short h) {
    return __builtin_bit_cast(float, (unsigned)h << 16);
}
__device__ inline float fexp2(float x) {
    float r;
    asm("v_exp_f32 %0, %1" : "=v"(r) : "v"(x));
    return r;
}
__device__ inline unsigned cvtpk(float a, float b) {   // low=bf16(a), high=bf16(b)
    unsigned r;
    asm("v_cvt_pk_bf16_f32 %0, %1, %2" : "=v"(r) : "v"(a), "v"(b));
    return r;
}

// ---------------- fused: all 4 casts + RoPE table, one launch ----------------
__global__ void cast_all(const float* __restrict__ x, const float* __restrict__ wqk,
                         const float* __restrict__ wv, const float* __restrict__ wo,
                         unsigned short* __restrict__ xb, unsigned short* __restrict__ wb,
                         float2* __restrict__ tab) {
    int idx = blockIdx.x * 256 + threadIdx.x;
    if (idx < 6291456) {
        const float* src; unsigned short* dst; int off;
        if (idx < 2097152)      { src = x;   dst = xb;             off = 0; }
        else if (idx < 4194304) { src = wqk; dst = wb;             off = 2097152; }
        else if (idx < 5242880) { src = wv;  dst = wb + 8388608;   off = 4194304; }
        else                    { src = wo;  dst = wb + 12582912;  off = 5242880; }
        int i = (idx - off) * 4;
        float4 v = *reinterpret_cast<const float4*>(src + i);
        ushort4 o;
        o.x = f2b(v.x); o.y = f2b(v.y); o.z = f2b(v.z); o.w = f2b(v.w);
        *reinterpret_cast<ushort4*>(dst + i) = o;
    } else {
        int k = idx - 6291456;              // 0..131071 = 2048 x 64
        int i = k & 63;
        int s = k >> 6;
        float inv = exp2f(-13.287712379549449f * (float)i * (1.0f / 64.0f));
        float ang = (float)s * inv;
        float sn, cs;
        sincosf(ang, &sn, &cs);
        tab[k] = make_float2(cs, sn);
    }
}

// ======== GEMM 128x256 2-phase core (r13-verified: 0 conflicts, counted vmcnt) ========
// MODE 0: fp32 C write. MODE 2: fused QKV epilogue (bx<8 Q-rope->qb, 8..15 K-rope->kb,
// 16..23 plain->vx).
template<int MODE>
__global__ __launch_bounds__(512) void gemm8p(const unsigned short* __restrict__ A,
                                              const unsigned short* __restrict__ Bw,
                                              void* __restrict__ Cout,
                                              unsigned short* __restrict__ qb,
                                              unsigned short* __restrict__ kbp,
                                              unsigned short* __restrict__ vx,
                                              const float2* __restrict__ tab,
                                              int M, int N, int K) {
    __shared__ __align__(16) char lds[98304];   // [A0 16K][B0 32K][A1 16K][B1 32K]
    int tid = threadIdx.x;
    int lane = tid & 63;
    int wid = tid >> 6;
    int wm = wid >> 2, wn = wid & 3;
    int row0 = blockIdx.y * 128;
    int col0 = blockIdx.x * 256;
    int lr = lane & 15, g = lane >> 4;

    const unsigned short* srcA[2];
    const unsigned short* srcB[4];
#pragma unroll
    for (int i = 0; i < 2; i++) {
        int chunk = i * 512 + tid;
        int ksub = chunk >> 9;
        int cw = chunk & 511;
        int row = cw >> 2, c = cw & 3;
        int cs = c ^ ((row >> 1) & 3);
        srcA[i] = A + (size_t)(row0 + row) * K + ksub * 32 + cs * 8;
    }
#pragma unroll
    for (int i = 0; i < 4; i++) {
        int chunk = i * 512 + tid;
        int ksub = chunk >> 10;
        int cw = chunk & 1023;
        int row = cw >> 2, c = cw & 3;
        int cs = c ^ ((row >> 1) & 3);
        srcB[i] = Bw + (size_t)(col0 + row) * K + ksub * 32 + cs * 8;
    }

    int offA[4][2], offB[4][2];
#pragma unroll
    for (int i = 0; i < 4; i++) {
        int row = wm * 64 + i * 16 + lr;
#pragma unroll
        for (int ks = 0; ks < 2; ks++)
            offA[i][ks] = ks * 8192 + row * 64 + ((g ^ ((row >> 1) & 3)) * 16);
    }
#pragma unroll
    for (int j = 0; j < 4; j++) {
        int row = wn * 64 + j * 16 + lr;
#pragma unroll
        for (int ks = 0; ks < 2; ks++)
            offB[j][ks] = ks * 16384 + row * 64 + ((g ^ ((row >> 1) & 3)) * 16);
    }

    f32x4 acc[4][4] = {};
    int NT = K >> 6;

#define STAGE8(t) {                                                                   \
        int kb_ = (t) * 64;                                                           \
        int bs_ = ((t) & 1) * 49152;                                                  \
        _Pragma("unroll")                                                             \
        for (int i_ = 0; i_ < 2; i_++)                                                \
            gload_lds16(srcA[i_] + kb_,                                               \
                (unsigned short*)(lds + bs_ + (i_ * 512 + (tid & ~63)) * 16));        \
        _Pragma("unroll")                                                             \
        for (int i_ = 0; i_ < 4; i_++)                                                \
            gload_lds16(srcB[i_] + kb_,                                               \
                (unsigned short*)(lds + bs_ + 16384 + (i_ * 512 + (tid & ~63)) * 16)); \
    }

    STAGE8(0);
    for (int t = 0; t < NT; ++t) {
        if (t + 1 < NT) {
            STAGE8(t + 1);
            asm volatile("s_waitcnt vmcnt(6)" ::: "memory");
        } else {
            asm volatile("s_waitcnt vmcnt(0)" ::: "memory");
        }
        __builtin_amdgcn_s_barrier();
        __builtin_amdgcn_sched_barrier(0);

        const char* ab = lds + (t & 1) * 49152;
        const char* bb = ab + 16384;

        bf16x8 b[4][2], a[2][2];
#pragma unroll
        for (int j = 0; j < 4; j++)
#pragma unroll
            for (int ks = 0; ks < 2; ks++)
                b[j][ks] = *reinterpret_cast<const bf16x8*>(bb + offB[j][ks]);
#pragma unroll
        for (int i = 0; i < 2; i++)
#pragma unroll
            for (int ks = 0; ks < 2; ks++)
                a[i][ks] = *reinterpret_cast<const bf16x8*>(ab + offA[i][ks]);
        asm volatile("s_waitcnt lgkmcnt(0)" ::: "memory");
        __builtin_amdgcn_sched_barrier(0);
        __builtin_amdgcn_s_setprio(1);
#pragma unroll
        for (int ks = 0; ks < 2; ks++)
#pragma unroll
            for (int i = 0; i < 2; i++)
#pragma unroll
                for (int j = 0; j < 4; j++)
                    acc[i][j] = MFMA16(a[i][ks], b[j][ks], acc[i][j], 0, 0, 0);
        __builtin_amdgcn_s_setprio(0);

        bf16x8 a2[2][2];
#pragma unroll
        for (int i = 0; i < 2; i++)
#pragma unroll
            for (int ks = 0; ks < 2; ks++)
                a2[i][ks] = *reinterpret_cast<const bf16x8*>(ab + offA[2 + i][ks]);
        asm volatile("s_waitcnt lgkmcnt(0)" ::: "memory");
        __builtin_amdgcn_sched_barrier(0);
        __builtin_amdgcn_s_barrier();
        __builtin_amdgcn_sched_barrier(0);
        __builtin_amdgcn_s_setprio(1);
#pragma unroll
        for (int ks = 0; ks < 2; ks++)
#pragma unroll
            for (int i = 0; i < 2; i++)
#pragma unroll
                for (int j = 0; j < 4; j++)
                    acc[2 + i][j] = MFMA16(a2[i][ks], b[j][ks], acc[2 + i][j], 0, 0, 0);
        __builtin_amdgcn_s_setprio(0);
    }
#undef STAGE8

    int orow = g * 4;
    if (MODE == 0) {
#pragma unroll
        for (int i = 0; i < 4; i++) {
#pragma unroll
            for (int j = 0; j < 4; j++) {
                int r0 = row0 + wm * 64 + i * 16 + orow;
                int c  = col0 + wn * 64 + j * 16 + lr;
#pragma unroll
                for (int r = 0; r < 4; r++)
                    ((float*)Cout)[(size_t)(r0 + r) * N + c] = acc[i][j][r];
            }
        }
    } else {
        int bx = blockIdx.x;
        if (bx < 16) {
            const bool isQ = (bx < 8);
            unsigned short* dst = isQ ? qb : kbp;
#pragma unroll
            for (int i = 0; i < 4; i++) {
#pragma unroll
                for (int j = 0; j < 4; j++) {
                    int c = col0 + wn * 64 + j * 16 + lr;
                    int cc = c & 2047;
                    int h = cc >> 7, d = cc & 127, i2 = d >> 1;
                    int odd = lr & 1;
#pragma unroll
                    for (int r = 0; r < 4; r++) {
                        int trow = row0 + wm * 64 + i * 16 + orow + r;
                        int s = trow & (SEQ - 1), bb2 = trow >> 11;
                        float v = acc[i][j][r];
                        float pv = __shfl_xor(v, 1);
                        float2 cssn = tab[s * 64 + i2];
                        float out = odd ? (pv * cssn.y + v * cssn.x)
                                        : (v * cssn.x - pv * cssn.y);
                        if (isQ) out *= QSCALE;
                        dst[((size_t)((bb2 * NH + h) * SEQ + s)) * HD + d] = f2b(out);
                    }
                }
            }
        } else {
#pragma unroll
            for (int i = 0; i < 4; i++) {
#pragma unroll
                for (int j = 0; j < 4; j++) {
                    int cc = col0 + wn * 64 + j * 16 + lr - 4096;
#pragma unroll
                    for (int r = 0; r < 4; r++) {
                        int trow = row0 + wm * 64 + i * 16 + orow + r;
                        vx[(size_t)trow * 2048 + cc] = f2b(acc[i][j][r]);
                    }
                }
            }
        }
    }
}

// ---------------- V transpose: vx[4096][2048] -> vt [bh][d][s], LDS-tiled 64x64 ----------------
__global__ __launch_bounds__(256) void v_tr(const unsigned short* __restrict__ vx,
                                            unsigned short* __restrict__ vt) {
    __shared__ unsigned short tl[64][68];
    int bid = blockIdx.x;                   // 32 st x 2 dt x 32 bh = 2048
    int st = bid & 31;
    int dt = (bid >> 5) & 1;
    int bh = bid >> 6;
    int b = bh >> 4, h = bh & 15;
    int tid = threadIdx.x;
    int rr = tid >> 2;
    int rc = (tid & 3) * 16;

    const unsigned short* src = vx + (size_t)(b * SEQ + st * 64 + rr) * 2048 + h * HD + dt * 64 + rc;
    uint4 v0 = *reinterpret_cast<const uint4*>(src);
    uint4 v1 = *reinterpret_cast<const uint4*>(src + 8);
    *reinterpret_cast<uint4*>(&tl[rr][rc]) = v0;
    *reinterpret_cast<uint4*>(&tl[rr][rc + 8]) = v1;
    __syncthreads();

    unsigned short tmp[16];
#pragma unroll
    for (int k = 0; k < 16; k++) tmp[k] = tl[rc + k][rr];
    unsigned short* dst = vt + (size_t)(bh * HD + dt * 64 + rr) * SEQ + st * 64 + rc;
    *reinterpret_cast<uint4*>(dst)     = *reinterpret_cast<const uint4*>(&tmp[0]);
    *reinterpret_cast<uint4*>(dst + 8) = *reinterpret_cast<const uint4*>(&tmp[8]);
}

// ---------------- flash attention v8: KVBLK=32, 18KB LDS -> 8 blocks/CU (2 waves/SIMD) ----------------
// Same verified structure as attn6 (pre-swizzled gload_lds K staging, counted vmcnt,
// swapped-operand in-lane softmax, defer-max, P LDS round-trip) with all KV dims halved.
// 2048 one-wave blocks, qt descending (heavy first), bh = bid&31 (XCD affinity).
__global__ __launch_bounds__(64, 2) void attn8(const unsigned short* __restrict__ Q,
                                               const unsigned short* __restrict__ Kb,
                                               const unsigned short* __restrict__ Vt,
                                               unsigned short* __restrict__ O) {
    __shared__ __align__(16) char lds[18432];   // K0 8K | K1 8K | P 2K

    int lane = threadIdx.x;
    int bid = blockIdx.x;
    int qt = 63 - (bid >> 5);       // heavy blocks first
    int bh = bid & 31;
    int q0 = qt * 32;
    int ktiles = qt + 1;            // KVBLK=32 tiles covering 0..q0+31
    int lr = lane & 15;
    int g  = lane >> 4;
    int g4 = g * 4;
    int lk = g * 8;

    const unsigned short* Qp = Q  + (size_t)bh * SEQ * HD;
    const unsigned short* Kp = Kb + (size_t)bh * SEQ * HD;
    const unsigned short* Vp = Vt + (size_t)bh * HD * SEQ;
    char* pl = lds + 16384;
    int b = bh >> 4;
    int h = bh & 15;

    int srcoff[8];
#pragma unroll
    for (int i2 = 0; i2 < 8; ++i2) {
        int r = i2 * 4 + g;                     // rows 0..31
        srcoff[i2] = r * HD + ((lr ^ (r & 7)) * 8);
    }

#define STAGEK32(bufbase, kvbase)                                                   \
    {                                                                               \
        const unsigned short* kbase = Kp + (size_t)(kvbase) * HD;                   \
        _Pragma("unroll")                                                           \
        for (int i2 = 0; i2 < 8; ++i2)                                              \
            gload_lds16(kbase + srcoff[i2],                                         \
                        (unsigned short*)(lds + (bufbase) + i2 * 1024));            \
    }

    bf16x8 qf[2][4];
#pragma unroll
    for (int f = 0; f < 2; f++)
#pragma unroll
        for (int kb = 0; kb < 4; kb++)
            qf[f][kb] = *reinterpret_cast<const bf16x8*>(Qp + (size_t)(q0 + f * 16 + lr) * HD + kb * 32 + lk);

    f32x4 oacc[2][8] = {};
    float m[2] = { -1e30f, -1e30f }, l[2] = { 0.0f, 0.0f };
    int qrow[2] = { q0 + lr, q0 + 16 + lr };

    STAGEK32(0, 0);

    int cur = 0;
    for (int t = 0; t < ktiles; ++t) {
        int kv0 = t * 32;
        if (t + 1 < ktiles) {
            STAGEK32((cur ^ 1) * 8192, kv0 + 32);
            asm volatile("s_waitcnt vmcnt(8)" ::: "memory");   // tile t's loads retired
        } else {
            asm volatile("s_waitcnt vmcnt(0)" ::: "memory");
        }
        __builtin_amdgcn_sched_barrier(0);

        char* kb_c = lds + cur * 8192;
        // ---- QK^T swapped: lane owns q = lane&15, 8 in-lane kv scores ----
        f32x4 s[2][2] = {};
#pragma unroll
        for (int kb = 0; kb < 4; kb++) {
#pragma unroll
            for (int jj = 0; jj < 2; jj++) {
                int row = jj * 16 + lr;
                int cin = ((kb * 4 + g) ^ (row & 7));
                bf16x8 kf = *reinterpret_cast<const bf16x8*>(kb_c + row * 256 + cin * 16);
                s[0][jj] = MFMA16(kf, qf[0][kb], s[0][jj], 0, 0, 0);
                s[1][jj] = MFMA16(kf, qf[1][kb], s[1][jj], 0, 0, 0);
            }
        }

        // ---- V prefetch (k = 32 -> single fragment per db) ----
        bf16x8 vf[8];
#pragma unroll
        for (int db = 0; db < 8; db++)
            vf[db] = *reinterpret_cast<const bf16x8*>(Vp + (size_t)(db * 16 + lr) * SEQ + kv0 + lk);

        // ---- in-lane online softmax (exp2 domain, defer-max) ----
#pragma unroll
        for (int f = 0; f < 2; f++) {
            int q = qrow[f];
            bool full = (kv0 + 31 <= q0 + f * 16);
            float mx = -1e30f;
            if (full) {
#pragma unroll
                for (int jj = 0; jj < 2; jj++)
#pragma unroll
                    for (int r = 0; r < 4; r++)
                        mx = fmaxf(mx, s[f][jj][r]);
            } else {
#pragma unroll
                for (int jj = 0; jj < 2; jj++)
#pragma unroll
                    for (int r = 0; r < 4; r++) {
                        int kv = kv0 + jj * 16 + g4 + r;
                        float v = (kv <= q) ? s[f][jj][r] : -1e30f;
                        s[f][jj][r] = v;
                        mx = fmaxf(mx, v);
                    }
            }
            mx = fmaxf(mx, __shfl_xor(mx, 16));
            mx = fmaxf(mx, __shfl_xor(mx, 32));

            if (!__all(mx <= m[f] + THRL2)) {
                float mn = fmaxf(m[f], mx);
                float sc = fexp2(m[f] - mn);
                m[f] = mn;
                l[f] *= sc;
#pragma unroll
                for (int db = 0; db < 8; db++)
#pragma unroll
                    for (int r = 0; r < 4; r++)
                        oacc[f][db][r] *= sc;
            }

            int row = f * 16 + lr;
            int rb = row * 64;                  // 64B per P row (32 kv x bf16)
            int sw = (row & 3) << 4;
            float rs = 0.0f;
#pragma unroll
            for (int jj = 0; jj < 2; jj++)
#pragma unroll
                for (int hh = 0; hh < 2; hh++) {
                    float p0 = fexp2(s[f][jj][2 * hh]     - m[f]);
                    float p1 = fexp2(s[f][jj][2 * hh + 1] - m[f]);
                    rs += p0 + p1;
                    unsigned pk = cvtpk(p0, p1);
                    int colb = jj * 32 + g * 8 + 4 * hh;
                    *reinterpret_cast<unsigned*>(pl + rb + (colb ^ sw)) = pk;
                }
            rs += __shfl_xor(rs, 16);
            rs += __shfl_xor(rs, 32);
            l[f] += rs;
        }

        asm volatile("s_waitcnt lgkmcnt(0)" ::: "memory");
        __builtin_amdgcn_sched_barrier(0);

        // ---- P fragments + swapped PV ----
        bf16x8 pb[2];
#pragma unroll
        for (int f = 0; f < 2; f++) {
            int row = f * 16 + lr;
            int off = row * 64 + ((g * 16) ^ ((row & 3) << 4));
            pb[f] = *reinterpret_cast<const bf16x8*>(pl + off);
        }
#pragma unroll
        for (int db = 0; db < 8; db++) {
            oacc[0][db] = MFMA16(vf[db], pb[0], oacc[0][db], 0, 0, 0);
            oacc[1][db] = MFMA16(vf[db], pb[1], oacc[1][db], 0, 0, 0);
        }

        cur ^= 1;
    }

#pragma unroll
    for (int f = 0; f < 2; f++) {
        float inv = 1.0f / l[f];
        int q = q0 + f * 16 + lr;
        unsigned short* op = O + ((size_t)(b * SEQ + q)) * DMODEL + h * HD;
#pragma unroll
        for (int db = 0; db < 8; db++) {
            ushort4 o4;
            o4.x = f2b(oacc[f][db][0] * inv);
            o4.y = f2b(oacc[f][db][1] * inv);
            o4.z = f2b(oacc[f][db][2] * inv);
            o4.w = f2b(oacc[f][db][3] * inv);
            *reinterpret_cast<ushort4*>(op + db * 16 + g4) = o4;
        }
    }
#undef STAGEK32
}

extern "C" void kernel_launch(void* const* d_in, const int* in_sizes, int n_in,
                              void* d_out, int out_size, void* d_ws, size_t ws_size,
                              hipStream_t stream) {
    const float* x   = (const float*)d_in[0];
    const float* wqk = (const float*)d_in[1];
    const float* wv  = (const float*)d_in[2];
    const float* wo  = (const float*)d_in[3];

    unsigned short* xb  = (unsigned short*)d_ws;            // [4096][2048]
    unsigned short* wb  = xb  + (size_t)8388608;            // [8192][2048]: wqk | wv | wo
    unsigned short* qb  = wb  + (size_t)16777216;           // [B][H][S][HD]
    unsigned short* kb  = qb  + (size_t)8388608;
    unsigned short* vx  = kb  + (size_t)8388608;            // [4096][2048] plain V
    unsigned short* vt  = vx  + (size_t)8388608;            // [B][H][HD][S]
    unsigned short* ao  = vt  + (size_t)8388608;            // [4096][2048]
    float2* tab = (float2*)(ao + (size_t)8388608);          // [2048][64]

    // fused casts + RoPE table (one launch)
    cast_all<<<25088, 256, 0, stream>>>(x, wqk, wv, wo, xb, wb, tab);

    // fused QKV projection + RoPE + layout: writes qb, kb, vx directly
    gemm8p<2><<<dim3(24, 32), 512, 0, stream>>>(xb, wb, nullptr, qb, kb, vx, tab, 4096, 6144, 2048);

    v_tr<<<2048, 256, 0, stream>>>(vx, vt);

    attn8<<<2048, 64, 0, stream>>>(qb, kb, vt, ao);

    // out projection
    gemm8p<0><<<dim3(8, 32), 512, 0, stream>>>(ao, wb + 12582912, d_out, nullptr, nullptr, nullptr, nullptr, 4096, 2048, 2048);
}